// Round 4
// baseline (1265.798 us; speedup 1.0000x reference)
//
#include <hip/hip_runtime.h>

// AdaptivePooling (reduce_mean, output 7x7) on NHWC fp32 x[16,250,250,256].
// TF/JAX bin edges for 250->7, computed in float32 exactly like the reference:
//   scale = float32(250/7) = 35.71428680419922
//   starts[i] = int(i*scale), ends[i] = ceil((i+1)*scale)  (fl(7*scale)==250.0)
//   starts = {0,35,71,107,142,178,214}, ends = {36,72,108,143,179,215,250}
// Bins overlap by one row/col at 6 of 7 boundaries (counts are 36 or 37);
// read amplification = (256/250)^2 = 1.0485.
// All rows in a bin share the same count, so mean-over-rows-then-cols
// equals sum/(nh*nw) -> single fused pass is numerically faithful (fp32).
//
// One block per output (b,i,j): 512 threads = 8 waves.
//   lane (0..63) owns channels [4*lane, 4*lane+4) via float4 (1KB/wave/load)
//   wave (0..7) stripes the bin's rows
// LDS reduce 8 partial float4 sums -> scale by 1/(nh*nw) -> float4 store.
//
// Occupancy: __launch_bounds__(512,8) -> 8 waves/EU = 32 waves/CU = 4
// blocks/CU resident; grid of 784 blocks <= 1024 slots -> single dispatch
// round, no tail. LDS 8KB/block -> 32KB/CU at 4 blocks, well under 160KB.

__global__ __launch_bounds__(512, 8) void AdaptivePooling_69028714381469_kernel(
    const float* __restrict__ x, float* __restrict__ out)
{
    constexpr int H = 250, W = 250, C = 256;
    const int starts[7] = {0, 35, 71, 107, 142, 178, 214};
    const int ends[7]   = {36, 72, 108, 143, 179, 215, 250};

    const int bid = blockIdx.x;            // b*49 + i*7 + j
    const int j = bid % 7;
    const int i = (bid / 7) % 7;
    const int b = bid / 49;

    const int lane = threadIdx.x & 63;
    const int wv   = threadIdx.x >> 6;     // 0..7

    const int h0 = starts[i], h1 = ends[i];
    const int w0 = starts[j], w1 = ends[j];
    const int nw = w1 - w0;

    const float* base = x + (size_t)b * H * W * C;

    float4 acc = make_float4(0.f, 0.f, 0.f, 0.f);
    for (int h = h0 + wv; h < h1; h += 8) {
        // contiguous 1KB per (h,w) position across the wave's 64 lanes
        const float4* p =
            reinterpret_cast<const float4*>(base + ((size_t)h * W + w0) * C) + lane;
        for (int w = 0; w < nw; ++w) {
            float4 v = p[(size_t)w * (C / 4)];
            acc.x += v.x; acc.y += v.y; acc.z += v.z; acc.w += v.w;
        }
    }

    __shared__ float4 red[8][64];
    red[wv][lane] = acc;
    __syncthreads();

    if (wv == 0) {
        float4 s = red[0][lane];
        #pragma unroll
        for (int k = 1; k < 8; ++k) {
            float4 t = red[k][lane];
            s.x += t.x; s.y += t.y; s.z += t.z; s.w += t.w;
        }
        const float inv = 1.0f / (float)((h1 - h0) * nw);
        s.x *= inv; s.y *= inv; s.z *= inv; s.w *= inv;
        // out[b][i][j][c]: flat float4 index = bid*64 + lane
        reinterpret_cast<float4*>(out)[(size_t)bid * 64 + lane] = s;
    }
}

extern "C" void kernel_launch(void* const* d_in, const int* in_sizes, int n_in,
                              void* d_out, int out_size, void* d_ws, size_t ws_size,
                              hipStream_t stream) {
    const float* x = (const float*)d_in[0];
    float* out = (float*)d_out;
    // grid = B * OH * OW = 16*7*7 = 784 blocks, 512 threads each (8 waves)
    AdaptivePooling_69028714381469_kernel<<<dim3(16 * 7 * 7), dim3(512), 0, stream>>>(x, out);
}